// Round 3
// baseline (311.887 us; speedup 1.0000x reference)
//
#include <hip/hip_runtime.h>

typedef __attribute__((ext_vector_type(8))) short bf16x8;
typedef __attribute__((ext_vector_type(4))) float f32x4;
typedef __attribute__((ext_vector_type(4))) unsigned short u16x4;

#define NEG 0.2f
#define LDST 136   // bf16 elems per LDS row: 272 B, 16B-aligned, 68 dw % 32 = 4 -> 2-way (free)
#define WROW 128   // Wbf row stride in bf16

__device__ __forceinline__ float lrelu(float x) { return x >= 0.0f ? x : NEG * x; }

__device__ __forceinline__ unsigned short f2bf(float x) {
    unsigned u = __builtin_bit_cast(unsigned, x);
    u += 0x7FFFu + ((u >> 16) & 1u);
    return (unsigned short)(u >> 16);
}

// ---- prep: Wbf[h][112][128] bf16; rows 0..99 = W_h, row 100 = W_h^T att_src,
// ---- row 101 = W_h^T att_dst, rows 102..111 = 0, cols 100..127 = 0.
extern "C" __global__ void prep_w(const float* __restrict__ W,
                                  const float* __restrict__ att_src,
                                  const float* __restrict__ att_dst,
                                  unsigned short* __restrict__ Wbf)
{
    const int h = blockIdx.x;      // 4 blocks
    const int f = threadIdx.x;     // 128 threads
    float ws = 0.0f, wd = 0.0f;
    if (f < 100) {
        for (int o = 0; o < 100; ++o) {
            float wv = W[(h * 100 + o) * 100 + f];
            ws = fmaf(att_src[h * 100 + o], wv, ws);
            wd = fmaf(att_dst[h * 100 + o], wv, wd);
        }
    }
    unsigned short* Wh = Wbf + h * 112 * WROW;
    for (int o = 0; o < 100; ++o)
        Wh[o * WROW + f] = (f < 100) ? f2bf(W[(h * 100 + o) * 100 + f]) : (unsigned short)0;
    Wh[100 * WROW + f] = f2bf(ws);   // 0 for f>=100
    Wh[101 * WROW + f] = f2bf(wd);
    for (int o = 102; o < 112; ++o) Wh[o * WROW + f] = 0;
}

// One block per t. 256 threads = 4 waves, 2 blocks/CU (LDS 63168 B).
// LDS: S [112][136] bf16 @0        : A_t^T staging (X), then E[i][j] per head
//      HT [112][136] bf16 @30464   : H^T[o][j] per head (+ a_s,a_d rows as cols 100/101)
//      tails @60928: sas[112], sad[112], ssi[112], sp[2][112] (f32)
//      sOut f32 [112][124] overlays S+HT at the end.
extern "C" __global__ void __launch_bounds__(256, 2)
gat_mfma2(const float* __restrict__ A, const unsigned short* __restrict__ Wbf,
          const float* __restrict__ bias, float* __restrict__ out)
{
    extern __shared__ char smem[];
    unsigned short* S  = (unsigned short*)(smem);
    unsigned short* HT = (unsigned short*)(smem + 30464);
    float* sas = (float*)(smem + 60928);
    float* sad = sas + 112;
    float* ssi = sad + 112;
    float* sp  = ssi + 112;            // [2][112]
    float* sOut = (float*)smem;        // [o][124] overlay

    const int t   = blockIdx.x;
    const int tid = threadIdx.x;
    const int w   = tid >> 6;
    const int l   = tid & 63;
    const int lr  = l & 15;
    const int lk  = l >> 4;
    const float* __restrict__ At = A + (size_t)t * 10000u;

    // zero all LDS (pads must be 0)
    for (int i = tid; i < 3948; i += 256) ((f32x4*)smem)[i] = (f32x4){0, 0, 0, 0};
    __syncthreads();

    // stage A_t^T -> S[n][f] bf16
    for (int idx = tid; idx < 10000; idx += 256) {
        int f = idx / 100, n = idx - f * 100;
        S[n * LDST + f] = f2bf(At[idx]);
    }
    __syncthreads();

    // per-wave persistent A-fragments: tile-rows row0=w, row1=w+4
    const int nrow = (w < 3) ? 2 : 1;
    const int row0 = w, row1 = w + 4;
    bf16x8 xf[2][4];
#pragma unroll
    for (int ks = 0; ks < 4; ++ks) {
        const int koff = ks * 32 + lk * 8;
        xf[0][ks] = *(const bf16x8*)(S + (row0 * 16 + lr) * LDST + koff);
        xf[1][ks] = (nrow > 1) ? *(const bf16x8*)(S + (row1 * 16 + lr) * LDST + koff)
                               : xf[0][ks];
    }

    f32x4 acc[2][7];
#pragma unroll
    for (int r = 0; r < 2; ++r)
#pragma unroll
        for (int c = 0; c < 7; ++c) acc[r][c] = (f32x4){0, 0, 0, 0};

    for (int h = 0; h < 4; ++h) {
        // ---- GEMM-1: c1 = X * Wbf_h^T  (B-frags straight from global/L2) ----
        f32x4 c1[2][7];
#pragma unroll
        for (int r = 0; r < 2; ++r)
#pragma unroll
            for (int c = 0; c < 7; ++c) c1[r][c] = (f32x4){0, 0, 0, 0};

        const unsigned short* __restrict__ Wh = Wbf + h * 112 * WROW;
        for (int ks = 0; ks < 4; ++ks) {
            const int koff = ks * 32 + lk * 8;
            bf16x8 b[7];
#pragma unroll
            for (int tn = 0; tn < 7; ++tn)
                b[tn] = *(const bf16x8*)(Wh + (tn * 16 + lr) * WROW + koff);
#pragma unroll
            for (int tn = 0; tn < 7; ++tn) {
                c1[0][tn] = __builtin_amdgcn_mfma_f32_16x16x32_bf16(xf[0][ks], b[tn], c1[0][tn], 0, 0, 0);
                if (nrow > 1)
                    c1[1][tn] = __builtin_amdgcn_mfma_f32_16x16x32_bf16(xf[1][ks], b[tn], c1[1][tn], 0, 0, 0);
            }
        }
        // write HT[o][j] bf16 ; cols 100/101 of C are a_s/a_d -> f32 arrays
        for (int r = 0; r < nrow; ++r) {
            const int j0 = (r ? row1 : row0) * 16 + 4 * lk;
#pragma unroll
            for (int tn = 0; tn < 7; ++tn) {
                const int o = tn * 16 + lr;
                u16x4 p;
                p.x = f2bf(c1[r][tn].x); p.y = f2bf(c1[r][tn].y);
                p.z = f2bf(c1[r][tn].z); p.w = f2bf(c1[r][tn].w);
                *(u16x4*)(HT + o * LDST + j0) = p;
            }
            if (lr == 4) *(f32x4*)(sas + j0) = c1[r][6];   // col 100 = a_s
            if (lr == 5) *(f32x4*)(sad + j0) = c1[r][6];   // col 101 = a_d
        }
        __syncthreads();   // (a) HT, a_s, a_d ready; prev E reads of S done

        // ---- E[i][j] = exp(lrelu(a_d[i]+a_s[j])) bf16 into S; row partial sums ----
        if (tid < 200) {
            const int i = tid >> 1, half = tid & 1;
            const float adi = sad[i];
            const int j0 = half * 50;
            unsigned* dst = (unsigned*)(S + i * LDST + j0);
            float sum = 0.0f;
            for (int jj = 0; jj < 50; jj += 2) {
                float e0 = __expf(lrelu(adi + sas[j0 + jj]));
                float e1 = __expf(lrelu(adi + sas[j0 + jj + 1]));
                sum += e0 + e1;
                dst[jj >> 1] = ((unsigned)f2bf(e1) << 16) | (unsigned)f2bf(e0);
            }
            sp[half * 112 + i] = sum;
        }
        __syncthreads();   // (b) E + sums ready
        if (tid < 100) ssi[tid] = 1.0f / (sp[tid] + sp[112 + tid]);

        // ---- PV: cp = E * H  (A = E rows from S, B = HT rows) ----
        f32x4 cp[2][7];
#pragma unroll
        for (int r = 0; r < 2; ++r)
#pragma unroll
            for (int c = 0; c < 7; ++c) cp[r][c] = (f32x4){0, 0, 0, 0};
        for (int ks = 0; ks < 4; ++ks) {
            const int koff = ks * 32 + lk * 8;
            bf16x8 a0 = *(const bf16x8*)(S + (row0 * 16 + lr) * LDST + koff);
            bf16x8 a1 = (nrow > 1) ? *(const bf16x8*)(S + (row1 * 16 + lr) * LDST + koff) : a0;
#pragma unroll
            for (int tn = 0; tn < 7; ++tn) {
                bf16x8 bb = *(const bf16x8*)(HT + (tn * 16 + lr) * LDST + koff);
                cp[0][tn] = __builtin_amdgcn_mfma_f32_16x16x32_bf16(a0, bb, cp[0][tn], 0, 0, 0);
                if (nrow > 1)
                    cp[1][tn] = __builtin_amdgcn_mfma_f32_16x16x32_bf16(a1, bb, cp[1][tn], 0, 0, 0);
            }
        }
        __syncthreads();   // (c) PV reads done (S/HT reusable); ssi visible

        // ---- acc += cp * (1/S_i): per-lane rows i0..i0+3 share ssi vector ----
        for (int r = 0; r < nrow; ++r) {
            const int i0 = (r ? row1 : row0) * 16 + 4 * lk;
            const f32x4 sv = *(const f32x4*)(ssi + i0);
#pragma unroll
            for (int tn = 0; tn < 7; ++tn)
                acc[r][tn] += cp[r][tn] * sv;
        }
    }

    // ---- epilogue: sOut[o][i] = lrelu(acc*0.25 + bias[o]) + (i==o) ----
    for (int r = 0; r < nrow; ++r) {
        const int i0 = (r ? row1 : row0) * 16 + 4 * lk;
#pragma unroll
        for (int tn = 0; tn < 7; ++tn) {
            const int o = tn * 16 + lr;
            const float b = (o < 100) ? bias[o] : 0.0f;
            f32x4 v;
            v.x = lrelu(acc[r][tn].x * 0.25f + b) + ((i0 + 0) == o ? 1.0f : 0.0f);
            v.y = lrelu(acc[r][tn].y * 0.25f + b) + ((i0 + 1) == o ? 1.0f : 0.0f);
            v.z = lrelu(acc[r][tn].z * 0.25f + b) + ((i0 + 2) == o ? 1.0f : 0.0f);
            v.w = lrelu(acc[r][tn].w * 0.25f + b) + ((i0 + 3) == o ? 1.0f : 0.0f);
            *(f32x4*)(sOut + o * 124 + i0) = v;
        }
    }
    __syncthreads();

    float* __restrict__ outT = out + (size_t)t * 10000u;
    for (int idx = tid; idx < 10000; idx += 256) {
        int o = idx / 100, i2 = idx - o * 100;
        outT[idx] = sOut[o * 124 + i2];
    }
}

extern "C" void kernel_launch(void* const* d_in, const int* in_sizes, int n_in,
                              void* d_out, int out_size, void* d_ws, size_t ws_size,
                              hipStream_t stream) {
    const float* A      = (const float*)d_in[0];
    const float* W      = (const float*)d_in[1];
    const float* attsrc = (const float*)d_in[2];
    const float* attdst = (const float*)d_in[3];
    const float* bias   = (const float*)d_in[4];
    float* outp = (float*)d_out;
    unsigned short* Wbf = (unsigned short*)d_ws;   // 4*112*128*2 = 114688 B

    const int T = in_sizes[0] / 10000;   // 1024

    prep_w<<<4, 128, 0, stream>>>(W, attsrc, attdst, Wbf);

    const int smem_bytes = 63168;
    hipFuncSetAttribute((const void*)gat_mfma2,
                        hipFuncAttributeMaxDynamicSharedMemorySize, smem_bytes);
    gat_mfma2<<<T, 256, smem_bytes, stream>>>(A, Wbf, bias, outp);
}